// Round 1
// baseline (2585.532 us; speedup 1.0000x reference)
//
#include <hip/hip_runtime.h>
#include <hip/hip_bf16.h>
#include <stdint.h>

typedef __bf16 bf16;
typedef __bf16 bf16x4 __attribute__((ext_vector_type(4)));
typedef __bf16 bf16x8 __attribute__((ext_vector_type(8)));
typedef float  f32x4  __attribute__((ext_vector_type(4)));

__device__ __forceinline__ f32x4 mfma16(bf16x8 a, bf16x8 b, f32x4 c) {
    return __builtin_amdgcn_mfma_f32_16x16x32_bf16(a, b, c, 0, 0, 0);
}

__device__ __forceinline__ void st_bf4(bf16* p, float a, float b, float c, float d) {
    bf16x4 v = { (bf16)a, (bf16)b, (bf16)c, (bf16)d };
    *(bf16x4*)p = v;
}

// ---------------------------------------------------------------------------
// Kernel 1: LN1 + cyclic shift + window partition + 8-head window attention
//           + proj + residual, one block per (batch, window).
// windowed token (w, t): shifted coords hs=wr*8+tr, ws=wc*8+tc;
// source/dest orig coords h=(hs+4)&63, v=(ws+4)&63 (roll by -4 fwd, +4 bwd).
// ---------------------------------------------------------------------------
__global__ __launch_bounds__(256) void k_attn(
    const float* __restrict__ x,
    const float* __restrict__ n1w, const float* __restrict__ n1b,
    const float* __restrict__ qkvw, const float* __restrict__ qkvb,
    const float* __restrict__ projw, const float* __restrict__ projb,
    const float* __restrict__ rpb,
    float* __restrict__ x1)
{
    __shared__ bf16 sX[64][264];   // LN'd window tokens (bf16), padded
    __shared__ bf16 sW[96][264];   // staged weights (qkv per head / proj chunk)
    __shared__ bf16 sO[64][264];   // attention output (all heads)
    __shared__ bf16 sQ[64][40];
    __shared__ bf16 sK[64][40];
    __shared__ bf16 sVT[32][72];   // V transposed: [d][token]
    __shared__ bf16 sP[64][72];    // softmax probs
    __shared__ float sRPB[1800];   // rpb_table 225x8

    const int tid = threadIdx.x;
    const int wv  = tid >> 6;      // wave 0..3 (= M-tile)
    const int ln  = tid & 63;
    const int l16 = ln & 15;
    const int lg  = ln >> 4;

    const int win = blockIdx.x;
    const int b   = win >> 6;
    const int w   = win & 63;
    const int wr  = w >> 3, wc = w & 7;

    for (int i = tid; i < 1800; i += 256) sRPB[i] = rpb[i];

    // ---- LN1 + shift + partition: wave wv handles rows wv*16..+15 ----
    for (int rr = 0; rr < 16; ++rr) {
        const int row = wv * 16 + rr;
        const int tr = row >> 3, tc = row & 7;
        const int hs = (wr * 8 + tr + 4) & 63;
        const int vs = (wc * 8 + tc + 4) & 63;
        const float* src = x + (((size_t)b << 12) + (hs << 6) + vs) * 256;
        float4 v = *(const float4*)(src + ln * 4);
        float s = v.x + v.y + v.z + v.w;
        float q = v.x*v.x + v.y*v.y + v.z*v.z + v.w*v.w;
        #pragma unroll
        for (int o = 32; o; o >>= 1) { s += __shfl_xor(s, o); q += __shfl_xor(q, o); }
        const float mean = s * (1.0f/256.0f);
        const float var  = q * (1.0f/256.0f) - mean * mean;
        const float rstd = rsqrtf(var + 1e-5f);
        float4 gw = *(const float4*)(n1w + ln*4);
        float4 gb = *(const float4*)(n1b + ln*4);
        st_bf4(&sX[row][ln*4],
               (v.x-mean)*rstd*gw.x + gb.x,
               (v.y-mean)*rstd*gw.y + gb.y,
               (v.z-mean)*rstd*gw.z + gb.z,
               (v.w-mean)*rstd*gw.w + gb.w);
    }
    __syncthreads();

    const float scale = 0.1767766952966369f;  // 32^-0.5
    const f32x4 zero = {};

    for (int h = 0; h < 8; ++h) {
        // stage qkv weights for this head: rows 0..31 q, 32..63 k, 64..95 v
        for (int i = tid; i < 96*64; i += 256) {
            const int r = i >> 6, c4 = (i & 63) << 2;
            const int g = (r < 32) ? (h*32 + r)
                        : ((r < 64) ? (256 + h*32 + r - 32) : (512 + h*32 + r - 64));
            float4 wf = *(const float4*)(qkvw + (size_t)g*256 + c4);
            st_bf4(&sW[r][c4], wf.x, wf.y, wf.z, wf.w);
        }
        __syncthreads();

        // ---- qkv GEMM: (64x256)@(256x96) ----
        f32x4 acc[6];
        #pragma unroll
        for (int nt = 0; nt < 6; ++nt) acc[nt] = zero;
        #pragma unroll
        for (int ks = 0; ks < 8; ++ks) {
            bf16x8 a = *(const bf16x8*)&sX[wv*16 + l16][lg*8 + ks*32];
            #pragma unroll
            for (int nt = 0; nt < 6; ++nt) {
                bf16x8 bb = *(const bf16x8*)&sW[nt*16 + l16][lg*8 + ks*32];
                acc[nt] = mfma16(a, bb, acc[nt]);
            }
        }
        #pragma unroll
        for (int nt = 0; nt < 6; ++nt) {
            const int n = nt*16 + l16;
            const int g = (n < 32) ? (h*32 + n)
                        : ((n < 64) ? (256 + h*32 + n - 32) : (512 + h*32 + n - 64));
            const float bias = qkvb[g];
            #pragma unroll
            for (int r = 0; r < 4; ++r) {
                const int tok = wv*16 + lg*4 + r;
                const float val = acc[nt][r] + bias;
                if (nt < 2)      sQ[tok][n] = (bf16)(val * scale);
                else if (nt < 4) sK[tok][n - 32] = (bf16)val;
                else             sVT[n - 64][tok] = (bf16)val;
            }
        }
        __syncthreads();

        // ---- QK^T (64x64, K=32) + bias + mask + softmax ----
        f32x4 at[4];
        {
            bf16x8 qa = *(const bf16x8*)&sQ[wv*16 + l16][lg*8];
            #pragma unroll
            for (int nt = 0; nt < 4; ++nt) {
                bf16x8 kb = *(const bf16x8*)&sK[nt*16 + l16][lg*8];
                at[nt] = mfma16(qa, kb, zero);
            }
        }
        #pragma unroll
        for (int nt = 0; nt < 4; ++nt) {
            const int m = nt*16 + l16;
            const int mr = m >> 3, mc = m & 7;
            const int hm = (wr < 7) ? 0 : ((mr < 4) ? 1 : 2);
            const int wm = (wc < 7) ? 0 : ((mc < 4) ? 1 : 2);
            #pragma unroll
            for (int r = 0; r < 4; ++r) {
                const int n = wv*16 + lg*4 + r;
                const int nr = n >> 3, ncc = n & 7;
                float bv = sRPB[((nr - mr + 7)*15 + (ncc - mc + 7))*8 + h];
                const int hn = (wr < 7) ? 0 : ((nr < 4) ? 1 : 2);
                const int wn = (wc < 7) ? 0 : ((ncc < 4) ? 1 : 2);
                if ((hn != hm) || (wn != wm)) bv -= 100.f;
                at[nt][r] += bv;
            }
        }
        #pragma unroll
        for (int r = 0; r < 4; ++r) {
            float mx = fmaxf(fmaxf(at[0][r], at[1][r]), fmaxf(at[2][r], at[3][r]));
            #pragma unroll
            for (int o = 8; o; o >>= 1) mx = fmaxf(mx, __shfl_xor(mx, o));
            float e0 = __expf(at[0][r] - mx);
            float e1 = __expf(at[1][r] - mx);
            float e2 = __expf(at[2][r] - mx);
            float e3 = __expf(at[3][r] - mx);
            float sm = e0 + e1 + e2 + e3;
            #pragma unroll
            for (int o = 8; o; o >>= 1) sm += __shfl_xor(sm, o);
            const float inv = 1.0f / sm;
            const int n = wv*16 + lg*4 + r;
            sP[n][ 0 + l16] = (bf16)(e0 * inv);
            sP[n][16 + l16] = (bf16)(e1 * inv);
            sP[n][32 + l16] = (bf16)(e2 * inv);
            sP[n][48 + l16] = (bf16)(e3 * inv);
        }
        __syncthreads();

        // ---- PV: (64x64)@(64x32) ----
        #pragma unroll
        for (int nt = 0; nt < 2; ++nt) {
            f32x4 a3 = zero;
            #pragma unroll
            for (int ks = 0; ks < 2; ++ks) {
                bf16x8 pa = *(const bf16x8*)&sP[wv*16 + l16][lg*8 + ks*32];
                bf16x8 vb = *(const bf16x8*)&sVT[nt*16 + l16][lg*8 + ks*32];
                a3 = mfma16(pa, vb, a3);
            }
            #pragma unroll
            for (int r = 0; r < 4; ++r)
                sO[wv*16 + lg*4 + r][h*32 + nt*16 + l16] = (bf16)a3[r];
        }
        __syncthreads();
    }

    // ---- proj: (64x256)@(256x256)^T in 4 chunks of 64 cols + residual ----
    for (int nc = 0; nc < 4; ++nc) {
        for (int i = tid; i < 64*64; i += 256) {
            const int r = i >> 6, c4 = (i & 63) << 2;
            float4 wf = *(const float4*)(projw + (size_t)(nc*64 + r)*256 + c4);
            st_bf4(&sW[r][c4], wf.x, wf.y, wf.z, wf.w);
        }
        __syncthreads();
        f32x4 acc[4];
        #pragma unroll
        for (int nt = 0; nt < 4; ++nt) acc[nt] = zero;
        #pragma unroll
        for (int ks = 0; ks < 8; ++ks) {
            bf16x8 a = *(const bf16x8*)&sO[wv*16 + l16][lg*8 + ks*32];
            #pragma unroll
            for (int nt = 0; nt < 4; ++nt) {
                bf16x8 bb = *(const bf16x8*)&sW[nt*16 + l16][lg*8 + ks*32];
                acc[nt] = mfma16(a, bb, acc[nt]);
            }
        }
        #pragma unroll
        for (int r = 0; r < 4; ++r) {
            const int tok = wv*16 + lg*4 + r;
            const int tr = tok >> 3, tc = tok & 7;
            const int hs = (wr*8 + tr + 4) & 63;
            const int vs = (wc*8 + tc + 4) & 63;
            const size_t base = (((size_t)b << 12) + (hs << 6) + vs) * 256;
            #pragma unroll
            for (int nt = 0; nt < 4; ++nt) {
                const int n = nc*64 + nt*16 + l16;
                x1[base + n] = acc[nt][r] + projb[n] + x[base + n];
            }
        }
        __syncthreads();
    }
}

// ---------------------------------------------------------------------------
// Kernel 2: LN2 -> bf16
// ---------------------------------------------------------------------------
__global__ __launch_bounds__(256) void k_ln2(
    const float* __restrict__ x1, const float* __restrict__ n2w,
    const float* __restrict__ n2b, bf16* __restrict__ xn2)
{
    const int tid = threadIdx.x;
    const int wv = tid >> 6, ln = tid & 63;
    const size_t row = (size_t)blockIdx.x * 4 + wv;
    const float* src = x1 + row * 256;
    float4 v = *(const float4*)(src + ln * 4);
    float s = v.x + v.y + v.z + v.w;
    float q = v.x*v.x + v.y*v.y + v.z*v.z + v.w*v.w;
    #pragma unroll
    for (int o = 32; o; o >>= 1) { s += __shfl_xor(s, o); q += __shfl_xor(q, o); }
    const float mean = s * (1.0f/256.0f);
    const float var  = q * (1.0f/256.0f) - mean * mean;
    const float rstd = rsqrtf(var + 1e-5f);
    float4 gw = *(const float4*)(n2w + ln*4);
    float4 gb = *(const float4*)(n2b + ln*4);
    st_bf4(xn2 + row*256 + ln*4,
           (v.x-mean)*rstd*gw.x + gb.x,
           (v.y-mean)*rstd*gw.y + gb.y,
           (v.z-mean)*rstd*gw.z + gb.z,
           (v.w-mean)*rstd*gw.w + gb.w);
}

// ---------------------------------------------------------------------------
// Kernel 3: fc12 (gate+feat) + SiLU fusion; processes one half (512 hidden cols)
// ---------------------------------------------------------------------------
__global__ __launch_bounds__(256) void k_fc12(
    const bf16* __restrict__ xn2, const float* __restrict__ fw,
    const float* __restrict__ fb, bf16* __restrict__ hidden, const int half)
{
    __shared__ bf16 sA[64][264];
    __shared__ bf16 sG[64][264];
    __shared__ bf16 sF[64][264];
    const int tid = threadIdx.x;
    const int wv = tid >> 6, ln = tid & 63, l16 = ln & 15, lg = ln >> 4;
    const int mblk = blockIdx.x >> 3, nblk = blockIdx.x & 7;
    const int g0 = half*512 + nblk*64;

    for (int i = tid; i < 64*32; i += 256) {
        const int r = i >> 5, c8 = (i & 31) << 3;
        *(uint4*)&sA[r][c8] = *(const uint4*)(xn2 + ((size_t)mblk*64 + r)*256 + c8);
    }
    for (int i = tid; i < 64*64; i += 256) {
        const int r = i >> 6, c4 = (i & 63) << 2;
        float4 a = *(const float4*)(fw + (size_t)(g0 + r)*256 + c4);
        st_bf4(&sG[r][c4], a.x, a.y, a.z, a.w);
        float4 c = *(const float4*)(fw + (size_t)(1024 + g0 + r)*256 + c4);
        st_bf4(&sF[r][c4], c.x, c.y, c.z, c.w);
    }
    __syncthreads();

    const f32x4 zero = {};
    f32x4 ag[4], af[4];
    #pragma unroll
    for (int nt = 0; nt < 4; ++nt) { ag[nt] = zero; af[nt] = zero; }
    #pragma unroll
    for (int ks = 0; ks < 8; ++ks) {
        bf16x8 a = *(const bf16x8*)&sA[wv*16 + l16][lg*8 + ks*32];
        #pragma unroll
        for (int nt = 0; nt < 4; ++nt) {
            bf16x8 bg = *(const bf16x8*)&sG[nt*16 + l16][lg*8 + ks*32];
            bf16x8 bf_ = *(const bf16x8*)&sF[nt*16 + l16][lg*8 + ks*32];
            ag[nt] = mfma16(a, bg, ag[nt]);
            af[nt] = mfma16(a, bf_, af[nt]);
        }
    }
    #pragma unroll
    for (int nt = 0; nt < 4; ++nt) {
        const int n = nt*16 + l16;
        #pragma unroll
        for (int r = 0; r < 4; ++r) {
            const float g = ag[nt][r] + fb[g0 + n];
            const float f = af[nt][r] + fb[1024 + g0 + n];
            const float hv = g / (1.0f + __expf(-g)) * f;
            const size_t t = (size_t)mblk*64 + wv*16 + lg*4 + r;
            hidden[t*512 + nblk*64 + n] = (bf16)hv;
        }
    }
}

// ---------------------------------------------------------------------------
// Kernel 4: fc2 over one hidden half (K=512) + residual / accumulate
// ---------------------------------------------------------------------------
__global__ __launch_bounds__(256) void k_fc2(
    const bf16* __restrict__ hidden, const float* __restrict__ fw,
    const float* __restrict__ fb, const float* __restrict__ x1,
    float* __restrict__ out, const int half)
{
    __shared__ bf16 sA[64][264];
    __shared__ bf16 sB[64][264];
    const int tid = threadIdx.x;
    const int wv = tid >> 6, ln = tid & 63, l16 = ln & 15, lg = ln >> 4;
    const int mblk = blockIdx.x >> 2, nblk = blockIdx.x & 3;

    const f32x4 zero = {};
    f32x4 acc[4];
    #pragma unroll
    for (int nt = 0; nt < 4; ++nt) acc[nt] = zero;

    for (int kc = 0; kc < 2; ++kc) {
        for (int i = tid; i < 64*32; i += 256) {
            const int r = i >> 5, c8 = (i & 31) << 3;
            *(uint4*)&sA[r][c8] =
                *(const uint4*)(hidden + ((size_t)mblk*64 + r)*512 + kc*256 + c8);
        }
        for (int i = tid; i < 64*64; i += 256) {
            const int r = i >> 6, c4 = (i & 63) << 2;
            float4 a = *(const float4*)(fw + (size_t)(nblk*64 + r)*1024
                                        + half*512 + kc*256 + c4);
            st_bf4(&sB[r][c4], a.x, a.y, a.z, a.w);
        }
        __syncthreads();
        #pragma unroll
        for (int ks = 0; ks < 8; ++ks) {
            bf16x8 a = *(const bf16x8*)&sA[wv*16 + l16][lg*8 + ks*32];
            #pragma unroll
            for (int nt = 0; nt < 4; ++nt) {
                bf16x8 bb = *(const bf16x8*)&sB[nt*16 + l16][lg*8 + ks*32];
                acc[nt] = mfma16(a, bb, acc[nt]);
            }
        }
        __syncthreads();
    }
    #pragma unroll
    for (int nt = 0; nt < 4; ++nt) {
        const int n = nblk*64 + nt*16 + l16;
        #pragma unroll
        for (int r = 0; r < 4; ++r) {
            const size_t t = (size_t)mblk*64 + wv*16 + lg*4 + r;
            const float base = half ? out[t*256 + n] : (x1[t*256 + n] + fb[n]);
            out[t*256 + n] = base + acc[nt][r];
        }
    }
}

// ---------------------------------------------------------------------------
extern "C" void kernel_launch(void* const* d_in, const int* in_sizes, int n_in,
                              void* d_out, int out_size, void* d_ws, size_t ws_size,
                              hipStream_t stream) {
    const float* x      = (const float*)d_in[0];
    const float* n1w    = (const float*)d_in[1];
    const float* n1b    = (const float*)d_in[2];
    const float* qkvw   = (const float*)d_in[3];
    const float* qkvb   = (const float*)d_in[4];
    const float* projw  = (const float*)d_in[5];
    const float* projb  = (const float*)d_in[6];
    const float* rpb    = (const float*)d_in[7];
    const float* n2w    = (const float*)d_in[8];
    const float* n2b    = (const float*)d_in[9];
    const float* fc12w  = (const float*)d_in[10];
    const float* fc12b  = (const float*)d_in[11];
    const float* fc2w   = (const float*)d_in[12];
    const float* fc2b   = (const float*)d_in[13];
    float* out = (float*)d_out;

    char* ws = (char*)d_ws;
    float* x1    = (float*)ws;                                  // 134217728 B
    bf16*  xn2   = (bf16*)(ws + 134217728);                     //  67108864 B
    bf16*  hidden= (bf16*)(ws + 134217728 + 67108864);          // 134217728 B

    k_attn<<<2048, 256, 0, stream>>>(x, n1w, n1b, qkvw, qkvb, projw, projb, rpb, x1);
    k_ln2<<<32768, 256, 0, stream>>>(x1, n2w, n2b, xn2);
    for (int half = 0; half < 2; ++half) {
        k_fc12<<<16384, 256, 0, stream>>>(xn2, fc12w, fc12b, hidden, half);
        k_fc2 <<< 8192, 256, 0, stream>>>(hidden, fc2w, fc2b, x1, out, half);
    }
}

// Round 2
// 1332.867 us; speedup vs baseline: 1.9398x; 1.9398x over previous
//
#include <hip/hip_runtime.h>
#include <hip/hip_bf16.h>
#include <stdint.h>

typedef __bf16 bf16;
typedef __bf16 bf16x4 __attribute__((ext_vector_type(4)));
typedef __bf16 bf16x8 __attribute__((ext_vector_type(8)));
typedef float  f32x4  __attribute__((ext_vector_type(4)));
typedef unsigned int u32;

__device__ __forceinline__ f32x4 mfma16(bf16x8 a, bf16x8 b, f32x4 c) {
    return __builtin_amdgcn_mfma_f32_16x16x32_bf16(a, b, c, 0, 0, 0);
}
__device__ __forceinline__ void st_bf4(bf16* p, float a, float b, float c, float d) {
    bf16x4 v = { (bf16)a, (bf16)b, (bf16)c, (bf16)d };
    *(bf16x4*)p = v;
}
// async global->LDS, 16B per lane; LDS dest = wave-uniform base + lane*16
__device__ __forceinline__ void gl16(const bf16* g, bf16* l) {
    __builtin_amdgcn_global_load_lds(
        (const __attribute__((address_space(1))) u32*)g,
        (__attribute__((address_space(3))) u32*)l, 16, 0, 0);
}

// ---------------------------------------------------------------------------
// weights f32 -> bf16 (concat: qkvw 196608 | projw 65536 | fc12w 524288 | fc2w 262144)
// ---------------------------------------------------------------------------
__global__ __launch_bounds__(256) void k_cvtw(
    const float* __restrict__ qkvw, const float* __restrict__ projw,
    const float* __restrict__ f12w, const float* __restrict__ f2w,
    bf16* __restrict__ wb)
{
    const int i = blockIdx.x * 256 + threadIdx.x;
    const int e = i * 4;
    const float* src; int off;
    if (e < 196608)      { src = qkvw; off = e; }
    else if (e < 262144) { src = projw; off = e - 196608; }
    else if (e < 786432) { src = f12w; off = e - 262144; }
    else                 { src = f2w;  off = e - 786432; }
    float4 v = *(const float4*)(src + off);
    st_bf4(wb + e, v.x, v.y, v.z, v.w);
}

// ---------------------------------------------------------------------------
// row LayerNorm (256 cols) -> bf16
// ---------------------------------------------------------------------------
__global__ __launch_bounds__(256) void k_ln(
    const float* __restrict__ in, const float* __restrict__ gw_,
    const float* __restrict__ gb_, bf16* __restrict__ o)
{
    const int tid = threadIdx.x;
    const int wv = tid >> 6, ln = tid & 63;
    const size_t row = (size_t)blockIdx.x * 4 + wv;
    const float* src = in + row * 256;
    float4 v = *(const float4*)(src + ln * 4);
    float s = v.x + v.y + v.z + v.w;
    float q = v.x*v.x + v.y*v.y + v.z*v.z + v.w*v.w;
    #pragma unroll
    for (int ofs = 32; ofs; ofs >>= 1) { s += __shfl_xor(s, ofs); q += __shfl_xor(q, ofs); }
    const float mean = s * (1.0f/256.0f);
    const float var  = q * (1.0f/256.0f) - mean * mean;
    const float rstd = rsqrtf(var + 1e-5f);
    float4 gw = *(const float4*)(gw_ + ln*4);
    float4 gb = *(const float4*)(gb_ + ln*4);
    st_bf4(o + row*256 + ln*4,
           (v.x-mean)*rstd*gw.x + gb.x, (v.y-mean)*rstd*gw.y + gb.y,
           (v.z-mean)*rstd*gw.z + gb.z, (v.w-mean)*rstd*gw.w + gb.w);
}

// ---------------------------------------------------------------------------
// QKV GEMM: [131072x256] @ [768x256]^T, 128x128 tiles, BK=32, swizzled LDS
// ---------------------------------------------------------------------------
__global__ __launch_bounds__(256) void k_qkv(
    const bf16* __restrict__ A, const bf16* __restrict__ Bw,
    const float* __restrict__ qkvb,
    bf16* __restrict__ Qb, bf16* __restrict__ Kb, bf16* __restrict__ Vb)
{
    __shared__ bf16 sA[128*32];
    __shared__ bf16 sB[128*32];
    const int tid = threadIdx.x, w = tid>>6, l = tid&63;
    const int l16 = l&15, lg = l>>4;
    const int wm = w>>1, wn = w&1;
    const int m0 = blockIdx.x<<7, n0 = blockIdx.y<<7;
    const int srow = l>>2;
    const int gk = ((l&3) ^ ((l>>3)&3)) << 3;   // pre-swizzled source k-slot
    const bf16* gA0 = A + (size_t)(m0 + w*32 + srow)*256 + gk;
    const bf16* gA1 = gA0 + 16*256;
    const bf16* gB0 = Bw + (size_t)(n0 + w*32 + srow)*256 + gk;
    const bf16* gB1 = gB0 + 16*256;
    bf16* lA0 = &sA[(w*32)*32];
    bf16* lA1 = &sA[(w*32+16)*32];
    bf16* lB0 = &sB[(w*32)*32];
    bf16* lB1 = &sB[(w*32+16)*32];
    const int slot = lg ^ ((l16>>1)&3);          // swizzled read slot
    int adA[4], adB[4];
    #pragma unroll
    for (int i=0;i<4;++i) {
        adA[i] = (wm*64 + i*16 + l16)*32 + slot*8;
        adB[i] = (wn*64 + i*16 + l16)*32 + slot*8;
    }
    f32x4 acc[4][4] = {};
    for (int ks = 0; ks < 8; ++ks) {
        gl16(gA0 + ks*32, lA0); gl16(gA1 + ks*32, lA1);
        gl16(gB0 + ks*32, lB0); gl16(gB1 + ks*32, lB1);
        __syncthreads();
        bf16x8 av[4], bv[4];
        #pragma unroll
        for (int i=0;i<4;++i) { av[i] = *(const bf16x8*)&sA[adA[i]]; bv[i] = *(const bf16x8*)&sB[adB[i]]; }
        #pragma unroll
        for (int mi=0;mi<4;++mi)
            #pragma unroll
            for (int ni=0;ni<4;++ni)
                acc[mi][ni] = mfma16(av[mi], bv[ni], acc[mi][ni]);
        __syncthreads();
    }
    #pragma unroll
    for (int ni=0;ni<4;++ni) {
        const int cg = n0 + wn*64 + ni*16 + l16;
        const int seg = cg >> 8, cs = cg & 255;
        bf16* dst = (seg==0) ? Qb : ((seg==1) ? Kb : Vb);
        const float mul = (seg==0) ? 0.1767766952966369f : 1.0f;
        const float bias = qkvb[cg];
        #pragma unroll
        for (int mi=0;mi<4;++mi) {
            const int row = m0 + wm*64 + mi*16 + lg*4;
            #pragma unroll
            for (int r=0;r<4;++r)
                dst[(size_t)(row+r)*256 + cs] = (bf16)((acc[mi][ni][r] + bias)*mul);
        }
    }
}

// ---------------------------------------------------------------------------
// window attention: one block per window, 8 heads, barrier-free head loop
// ---------------------------------------------------------------------------
__global__ __launch_bounds__(256) void k_attn(
    const bf16* __restrict__ Qb, const bf16* __restrict__ Kb,
    const bf16* __restrict__ Vb, const float* __restrict__ rpb,
    bf16* __restrict__ ao)
{
    __shared__ bf16 sK[64][264];
    __shared__ bf16 sVT[256][72];
    __shared__ bf16 sP[64][72];
    const int tid = threadIdx.x;
    const int wv = tid>>6, l = tid&63, l16 = l&15, lg = l>>4;
    const int win = blockIdx.x, b = win>>6, ww = win&63;
    const int wr = ww>>3, wc = ww&7;

    // stage K (contiguous global reads)
    for (int idx = tid; idx < 2048; idx += 256) {
        const int tok = idx>>5, c8 = idx&31;
        const int tr = tok>>3, tc = tok&7;
        const int hs = (wr*8+tr+4)&63, vs = (wc*8+tc+4)&63;
        const size_t grow = ((size_t)b<<12) + (hs<<6) + vs;
        *(bf16x8*)&sK[tok][c8*8] = *(const bf16x8*)(Kb + grow*256 + c8*8);
    }
    // stage V transposed (tok==lane mapping -> conflict-free LDS writes)
    for (int idx = tid; idx < 2048; idx += 256) {
        const int tok = idx&63, c8 = idx>>6;
        const int tr = tok>>3, tc = tok&7;
        const int hs = (wr*8+tr+4)&63, vs = (wc*8+tc+4)&63;
        const size_t grow = ((size_t)b<<12) + (hs<<6) + vs;
        bf16x8 vvv = *(const bf16x8*)(Vb + grow*256 + c8*8);
        #pragma unroll
        for (int j=0;j<8;++j) sVT[c8*8+j][tok] = vvv[j];
    }
    // Q fragments in registers (8 heads)
    const int qtok = wv*16 + l16;
    const int qtr = qtok>>3, qtc = qtok&7;
    const int qhs = (wr*8+qtr+4)&63, qvs = (wc*8+qtc+4)&63;
    const size_t qrow = ((size_t)b<<12) + (qhs<<6) + qvs;
    bf16x8 qf[8];
    #pragma unroll
    for (int h=0;h<8;++h) qf[h] = *(const bf16x8*)(Qb + qrow*256 + h*32 + lg*8);
    __syncthreads();

    const f32x4 zero = {};
    for (int h=0; h<8; ++h) {
        f32x4 at[4];
        #pragma unroll
        for (int nt=0;nt<4;++nt)
            at[nt] = mfma16(qf[h], *(const bf16x8*)&sK[nt*16+l16][h*32+lg*8], zero);
        #pragma unroll
        for (int nt=0;nt<4;++nt) {
            const int m = nt*16 + l16;          // key token
            const int mr = m>>3, mc = m&7;
            const int hm = (wr<7)?0:((mr<4)?1:2);
            const int wmg = (wc<7)?0:((mc<4)?1:2);
            #pragma unroll
            for (int r=0;r<4;++r) {
                const int n = wv*16 + lg*4 + r; // query token
                const int nr = n>>3, ncc = n&7;
                float bv = rpb[((nr-mr+7)*15 + (ncc-mc+7))*8 + h];
                const int hn = (wr<7)?0:((nr<4)?1:2);
                const int wn_ = (wc<7)?0:((ncc<4)?1:2);
                if ((hn!=hm)||(wn_!=wmg)) bv -= 100.f;
                at[nt][r] += bv;
            }
        }
        #pragma unroll
        for (int r=0;r<4;++r) {
            float mx = fmaxf(fmaxf(at[0][r],at[1][r]), fmaxf(at[2][r],at[3][r]));
            #pragma unroll
            for (int ofs=8;ofs;ofs>>=1) mx = fmaxf(mx, __shfl_xor(mx,ofs));
            float e0 = __expf(at[0][r]-mx), e1 = __expf(at[1][r]-mx);
            float e2 = __expf(at[2][r]-mx), e3 = __expf(at[3][r]-mx);
            float sm = e0+e1+e2+e3;
            #pragma unroll
            for (int ofs=8;ofs;ofs>>=1) sm += __shfl_xor(sm,ofs);
            const float inv = 1.0f/sm;
            const int n = wv*16 + lg*4 + r;
            sP[n][ 0+l16] = (bf16)(e0*inv);
            sP[n][16+l16] = (bf16)(e1*inv);
            sP[n][32+l16] = (bf16)(e2*inv);
            sP[n][48+l16] = (bf16)(e3*inv);
        }
        #pragma unroll
        for (int nt=0;nt<2;++nt) {
            f32x4 o = zero;
            #pragma unroll
            for (int ks=0;ks<2;++ks) {
                bf16x8 pa = *(const bf16x8*)&sP[wv*16+l16][ks*32+lg*8];
                bf16x8 vb = *(const bf16x8*)&sVT[h*32+nt*16+l16][ks*32+lg*8];
                o = mfma16(pa, vb, o);
            }
            #pragma unroll
            for (int r=0;r<4;++r)
                ao[((size_t)win*64 + wv*16 + lg*4 + r)*256 + h*32 + nt*16 + l16] = (bf16)o[r];
        }
    }
}

// ---------------------------------------------------------------------------
// proj GEMM (128x256, K=256) + reverse-shift scatter + residual + LN2 fused
// ---------------------------------------------------------------------------
__global__ __launch_bounds__(256) void k_proj(
    const bf16* __restrict__ ao, const bf16* __restrict__ Bw,
    const float* __restrict__ projb, const float* __restrict__ x,
    const float* __restrict__ n2w, const float* __restrict__ n2b,
    float* __restrict__ out, bf16* __restrict__ xn2)
{
    __shared__ bf16 sA[128*32];
    __shared__ bf16 sB[256*32];
    const int tid = threadIdx.x, w = tid>>6, l = tid&63;
    const int l16 = l&15, lg = l>>4;
    const int m0 = blockIdx.x<<7;
    const int srow = l>>2;
    const int gk = ((l&3) ^ ((l>>3)&3)) << 3;
    const bf16* gA0 = ao + (size_t)(m0 + w*32 + srow)*256 + gk;
    const bf16* gA1 = gA0 + 16*256;
    const bf16* gB0 = Bw + (size_t)(w*64 + srow)*256 + gk;
    bf16* lA0 = &sA[(w*32)*32];
    bf16* lA1 = &sA[(w*32+16)*32];
    bf16* lB0 = &sB[(w*64)*32];
    const int slot = lg ^ ((l16>>1)&3);
    const int adA0 = (w*32 + l16)*32 + slot*8;
    const int adA1 = (w*32+16 + l16)*32 + slot*8;
    f32x4 acc[2][16] = {};
    for (int ks=0; ks<8; ++ks) {
        gl16(gA0 + ks*32, lA0); gl16(gA1 + ks*32, lA1);
        #pragma unroll
        for (int i=0;i<4;++i)
            gl16(gB0 + i*16*256 + ks*32, lB0 + i*16*32);
        __syncthreads();
        bf16x8 a0 = *(const bf16x8*)&sA[adA0];
        bf16x8 a1 = *(const bf16x8*)&sA[adA1];
        #pragma unroll
        for (int nj=0;nj<16;++nj) {
            bf16x8 bvv = *(const bf16x8*)&sB[(nj*16 + l16)*32 + slot*8];
            acc[0][nj] = mfma16(a0, bvv, acc[0][nj]);
            acc[1][nj] = mfma16(a1, bvv, acc[1][nj]);
        }
        __syncthreads();
    }
    #pragma unroll
    for (int mi=0;mi<2;++mi) {
        #pragma unroll
        for (int rr=0;rr<4;++rr) {
            const int rgw = m0 + w*32 + mi*16 + lg*4 + rr;   // window-order row
            const int win = rgw>>6, tok = rgw&63;
            const int bb = win>>6, wwi = win&63;
            const int wr = wwi>>3, wc = wwi&7, tr = tok>>3, tc = tok&7;
            const int hs = (wr*8+tr+4)&63, vs = (wc*8+tc+4)&63;
            const size_t grow = ((size_t)bb<<12) + (hs<<6) + vs;
            float vals[16]; float s=0.f, s2=0.f;
            #pragma unroll
            for (int nj=0;nj<16;++nj) {
                const int col = nj*16 + l16;
                const float t = acc[mi][nj][rr] + projb[col] + x[grow*256 + col];
                vals[nj] = t; s += t; s2 += t*t;
            }
            #pragma unroll
            for (int ofs=8;ofs;ofs>>=1){ s += __shfl_xor(s,ofs); s2 += __shfl_xor(s2,ofs); }
            const float mean = s*(1.f/256.f);
            const float rstd = rsqrtf(s2*(1.f/256.f) - mean*mean + 1e-5f);
            #pragma unroll
            for (int nj=0;nj<16;++nj) {
                const int col = nj*16 + l16;
                out[grow*256+col] = vals[nj];
                xn2[grow*256+col] = (bf16)((vals[nj]-mean)*rstd*n2w[col] + n2b[col]);
            }
        }
    }
}

// ---------------------------------------------------------------------------
// fc12: gate+feat 128x64-pair tiles, SiLU fused
// ---------------------------------------------------------------------------
__global__ __launch_bounds__(256) void k_fc12(
    const bf16* __restrict__ xn2, const bf16* __restrict__ w12,
    const float* __restrict__ fb, bf16* __restrict__ hidden, const int half)
{
    __shared__ bf16 sA[128*32];
    __shared__ bf16 sG[64*32];
    __shared__ bf16 sF[64*32];
    const int tid = threadIdx.x, w = tid>>6, l = tid&63;
    const int l16 = l&15, lg = l>>4;
    const int m0 = blockIdx.x<<7;
    const int g0 = half*512 + (blockIdx.y<<6);
    const int srow = l>>2;
    const int gk = ((l&3) ^ ((l>>3)&3)) << 3;
    const bf16* gA0 = xn2 + (size_t)(m0 + w*32 + srow)*256 + gk;
    const bf16* gA1 = gA0 + 16*256;
    const bf16* gG = w12 + (size_t)(g0 + w*16 + srow)*256 + gk;
    const bf16* gF = w12 + (size_t)(1024 + g0 + w*16 + srow)*256 + gk;
    bf16* lA0 = &sA[(w*32)*32];
    bf16* lA1 = &sA[(w*32+16)*32];
    bf16* lG = &sG[(w*16)*32];
    bf16* lF = &sF[(w*16)*32];
    const int slot = lg ^ ((l16>>1)&3);
    const int adA0 = (w*32 + l16)*32 + slot*8;
    const int adA1 = (w*32+16 + l16)*32 + slot*8;
    f32x4 ag[2][4] = {}, af[2][4] = {};
    for (int ks=0;ks<8;++ks) {
        gl16(gA0 + ks*32, lA0); gl16(gA1 + ks*32, lA1);
        gl16(gG + ks*32, lG);   gl16(gF + ks*32, lF);
        __syncthreads();
        bf16x8 a0 = *(const bf16x8*)&sA[adA0];
        bf16x8 a1 = *(const bf16x8*)&sA[adA1];
        #pragma unroll
        for (int ni=0;ni<4;++ni) {
            bf16x8 bg = *(const bf16x8*)&sG[(ni*16+l16)*32 + slot*8];
            bf16x8 bff = *(const bf16x8*)&sF[(ni*16+l16)*32 + slot*8];
            ag[0][ni] = mfma16(a0,bg,ag[0][ni]);
            ag[1][ni] = mfma16(a1,bg,ag[1][ni]);
            af[0][ni] = mfma16(a0,bff,af[0][ni]);
            af[1][ni] = mfma16(a1,bff,af[1][ni]);
        }
        __syncthreads();
    }
    #pragma unroll
    for (int mi=0;mi<2;++mi)
    #pragma unroll
    for (int ni=0;ni<4;++ni) {
        const int col = ni*16 + l16;
        const float bg_ = fb[g0+col];
        const float bf_ = fb[1024+g0+col];
        #pragma unroll
        for (int r=0;r<4;++r) {
            const float g = ag[mi][ni][r] + bg_;
            const float f = af[mi][ni][r] + bf_;
            const float hv = g/(1.f+__expf(-g))*f;
            const size_t row = m0 + w*32 + mi*16 + lg*4 + r;
            hidden[row*512 + (g0 - half*512) + col] = (bf16)hv;
        }
    }
}

// ---------------------------------------------------------------------------
// fc2 over one hidden half (K=512), accumulates in-place into d_out (holds x1)
// ---------------------------------------------------------------------------
__global__ __launch_bounds__(256) void k_fc2(
    const bf16* __restrict__ hidden, const bf16* __restrict__ w2,
    const float* __restrict__ fb, float* __restrict__ out, const int half)
{
    __shared__ bf16 sA[128*32];
    __shared__ bf16 sB[256*32];
    const int tid = threadIdx.x, w = tid>>6, l = tid&63;
    const int l16 = l&15, lg = l>>4;
    const int m0 = blockIdx.x<<7;
    const int srow = l>>2;
    const int gk = ((l&3) ^ ((l>>3)&3)) << 3;
    const bf16* gA0 = hidden + (size_t)(m0 + w*32 + srow)*512 + gk;
    const bf16* gA1 = gA0 + 16*512;
    const bf16* gB0 = w2 + (size_t)(w*64 + srow)*1024 + half*512 + gk;
    bf16* lA0 = &sA[(w*32)*32];
    bf16* lA1 = &sA[(w*32+16)*32];
    bf16* lB0 = &sB[(w*64)*32];
    const int slot = lg ^ ((l16>>1)&3);
    const int adA0 = (w*32 + l16)*32 + slot*8;
    const int adA1 = (w*32+16 + l16)*32 + slot*8;
    f32x4 acc[2][16] = {};
    for (int ks=0;ks<16;++ks) {
        gl16(gA0 + ks*32, lA0); gl16(gA1 + ks*32, lA1);
        #pragma unroll
        for (int i=0;i<4;++i)
            gl16(gB0 + (size_t)i*16*1024 + ks*32, lB0 + i*16*32);
        __syncthreads();
        bf16x8 a0 = *(const bf16x8*)&sA[adA0];
        bf16x8 a1 = *(const bf16x8*)&sA[adA1];
        #pragma unroll
        for (int nj=0;nj<16;++nj) {
            bf16x8 bvv = *(const bf16x8*)&sB[(nj*16+l16)*32 + slot*8];
            acc[0][nj] = mfma16(a0,bvv,acc[0][nj]);
            acc[1][nj] = mfma16(a1,bvv,acc[1][nj]);
        }
        __syncthreads();
    }
    #pragma unroll
    for (int mi=0;mi<2;++mi)
    #pragma unroll
    for (int nj=0;nj<16;++nj) {
        const int col = nj*16 + l16;
        const float bias = (half==0) ? fb[col] : 0.f;
        #pragma unroll
        for (int r=0;r<4;++r) {
            const size_t row = m0 + w*32 + mi*16 + lg*4 + r;
            out[row*256+col] += acc[mi][nj][r] + bias;
        }
    }
}

// ---------------------------------------------------------------------------
extern "C" void kernel_launch(void* const* d_in, const int* in_sizes, int n_in,
                              void* d_out, int out_size, void* d_ws, size_t ws_size,
                              hipStream_t stream) {
    const float* x      = (const float*)d_in[0];
    const float* n1w    = (const float*)d_in[1];
    const float* n1b    = (const float*)d_in[2];
    const float* qkvw   = (const float*)d_in[3];
    const float* qkvb   = (const float*)d_in[4];
    const float* projw  = (const float*)d_in[5];
    const float* projb  = (const float*)d_in[6];
    const float* rpb    = (const float*)d_in[7];
    const float* n2w    = (const float*)d_in[8];
    const float* n2b    = (const float*)d_in[9];
    const float* fc12w  = (const float*)d_in[10];
    const float* fc12b  = (const float*)d_in[11];
    const float* fc2w   = (const float*)d_in[12];
    const float* fc2b   = (const float*)d_in[13];
    float* out = (float*)d_out;

    char* ws = (char*)d_ws;
    bf16* wb       = (bf16*)ws;                    // 2 MB converted weights
    bf16* qkvw_bf  = wb;
    bf16* projw_bf = wb + 196608;
    bf16* f12w_bf  = wb + 262144;
    bf16* f2w_bf   = wb + 786432;
    bf16* Qb  = (bf16*)(ws + 2097152);             // 64 MB
    bf16* Kb  = (bf16*)(ws + 69206016);            // 64 MB
    bf16* Vb  = (bf16*)(ws + 136314880);           // 64 MB
    bf16* xn1 = (bf16*)(ws + 203423744);           // 64 MB (reused as ao)
    bf16* ao  = (bf16*)(ws + 203423744);
    bf16* xn2 = (bf16*)(ws + 2097152);             // over Qb (dead)
    bf16* hid = (bf16*)(ws + 69206016);            // 128 MB over Kb,Vb (dead)

    k_cvtw<<<1024, 256, 0, stream>>>(qkvw, projw, fc12w, fc2w, wb);
    k_ln<<<32768, 256, 0, stream>>>(x, n1w, n1b, xn1);
    k_qkv<<<dim3(1024, 6), 256, 0, stream>>>(xn1, qkvw_bf, qkvb, Qb, Kb, Vb);
    k_attn<<<2048, 256, 0, stream>>>(Qb, Kb, Vb, rpb, ao);
    k_proj<<<1024, 256, 0, stream>>>(ao, projw_bf, projb, x, n2w, n2b, out, xn2);
    for (int half = 0; half < 2; ++half) {
        k_fc12<<<dim3(1024, 8), 256, 0, stream>>>(xn2, f12w_bf, fc12b, hid, half);
        k_fc2 <<<1024, 256, 0, stream>>>(hid, f2w_bf, fc2b, out, half);
    }
}

// Round 3
// 978.008 us; speedup vs baseline: 2.6437x; 1.3628x over previous
//
#include <hip/hip_runtime.h>
#include <hip/hip_bf16.h>
#include <stdint.h>

typedef __bf16 bf16;
typedef __bf16 bf16x4 __attribute__((ext_vector_type(4)));
typedef __bf16 bf16x8 __attribute__((ext_vector_type(8)));
typedef float  f32x4  __attribute__((ext_vector_type(4)));
typedef unsigned int u32;

__device__ __forceinline__ f32x4 mfma16(bf16x8 a, bf16x8 b, f32x4 c) {
    return __builtin_amdgcn_mfma_f32_16x16x32_bf16(a, b, c, 0, 0, 0);
}
__device__ __forceinline__ void st_bf4(bf16* p, float a, float b, float c, float d) {
    bf16x4 v = { (bf16)a, (bf16)b, (bf16)c, (bf16)d };
    *(bf16x4*)p = v;
}
// async global->LDS, 16B per lane; LDS dest = wave-uniform base + lane*16
__device__ __forceinline__ void gl16(const bf16* g, bf16* l) {
    __builtin_amdgcn_global_load_lds(
        (const __attribute__((address_space(1))) u32*)g,
        (__attribute__((address_space(3))) u32*)l, 16, 0, 0);
}

// ---------------------------------------------------------------------------
// weights f32 -> bf16 (concat: qkvw 196608 | projw 65536 | fc12w 524288 | fc2w 262144)
// ---------------------------------------------------------------------------
__global__ __launch_bounds__(256) void k_cvtw(
    const float* __restrict__ qkvw, const float* __restrict__ projw,
    const float* __restrict__ f12w, const float* __restrict__ f2w,
    bf16* __restrict__ wb)
{
    const int i = blockIdx.x * 256 + threadIdx.x;
    const int e = i * 4;
    const float* src; int off;
    if (e < 196608)      { src = qkvw; off = e; }
    else if (e < 262144) { src = projw; off = e - 196608; }
    else if (e < 786432) { src = f12w; off = e - 262144; }
    else                 { src = f2w;  off = e - 786432; }
    float4 v = *(const float4*)(src + off);
    st_bf4(wb + e, v.x, v.y, v.z, v.w);
}

// ---------------------------------------------------------------------------
// bias+mask table: tab[type][h][m(key)][n(query)], 4*8*64*64 = 131072 f32
// ---------------------------------------------------------------------------
__global__ __launch_bounds__(256) void k_mkbias(
    const float* __restrict__ rpb, float* __restrict__ tab)
{
    const int idx = blockIdx.x * 256 + threadIdx.x;
    const int type = idx >> 15, h = (idx >> 12) & 7, m = (idx >> 6) & 63, n = idx & 63;
    const int mr = m >> 3, mc = m & 7, nr = n >> 3, nc = n & 7;
    float bv = rpb[((nr - mr + 7) * 15 + (nc - mc + 7)) * 8 + h];
    const int ter = type >> 1, tec = type & 1;
    const int hm = ter ? ((mr < 4) ? 1 : 2) : 0;
    const int wm = tec ? ((mc < 4) ? 1 : 2) : 0;
    const int hn = ter ? ((nr < 4) ? 1 : 2) : 0;
    const int wn = tec ? ((nc < 4) ? 1 : 2) : 0;
    if (hm != hn || wm != wn) bv -= 100.f;
    tab[idx] = bv;
}

// ---------------------------------------------------------------------------
// row LayerNorm (256 cols) -> bf16
// ---------------------------------------------------------------------------
__global__ __launch_bounds__(256) void k_ln(
    const float* __restrict__ in, const float* __restrict__ gw_,
    const float* __restrict__ gb_, bf16* __restrict__ o)
{
    const int tid = threadIdx.x;
    const int wv = tid >> 6, ln = tid & 63;
    const size_t row = (size_t)blockIdx.x * 4 + wv;
    const float* src = in + row * 256;
    float4 v = *(const float4*)(src + ln * 4);
    float s = v.x + v.y + v.z + v.w;
    float q = v.x*v.x + v.y*v.y + v.z*v.z + v.w*v.w;
    #pragma unroll
    for (int ofs = 32; ofs; ofs >>= 1) { s += __shfl_xor(s, ofs); q += __shfl_xor(q, ofs); }
    const float mean = s * (1.0f/256.0f);
    const float var  = q * (1.0f/256.0f) - mean * mean;
    const float rstd = rsqrtf(var + 1e-5f);
    float4 gw = *(const float4*)(gw_ + ln*4);
    float4 gb = *(const float4*)(gb_ + ln*4);
    st_bf4(o + row*256 + ln*4,
           (v.x-mean)*rstd*gw.x + gb.x, (v.y-mean)*rstd*gw.y + gb.y,
           (v.z-mean)*rstd*gw.z + gb.z, (v.w-mean)*rstd*gw.w + gb.w);
}

// ---------------------------------------------------------------------------
// QKV GEMM: [131072x256] @ [768x256]^T, 128x128 tiles, BK=32, swizzled LDS
// ---------------------------------------------------------------------------
__global__ __launch_bounds__(256) void k_qkv(
    const bf16* __restrict__ A, const bf16* __restrict__ Bw,
    const float* __restrict__ qkvb,
    bf16* __restrict__ Qb, bf16* __restrict__ Kb, bf16* __restrict__ Vb)
{
    __shared__ bf16 sA[128*32];
    __shared__ bf16 sB[128*32];
    const int tid = threadIdx.x, w = tid>>6, l = tid&63;
    const int l16 = l&15, lg = l>>4;
    const int wm = w>>1, wn = w&1;
    const int m0 = blockIdx.x<<7, n0 = blockIdx.y<<7;
    const int srow = l>>2;
    const int gk = ((l&3) ^ ((l>>3)&3)) << 3;
    const bf16* gA0 = A + (size_t)(m0 + w*32 + srow)*256 + gk;
    const bf16* gA1 = gA0 + 16*256;
    const bf16* gB0 = Bw + (size_t)(n0 + w*32 + srow)*256 + gk;
    const bf16* gB1 = gB0 + 16*256;
    bf16* lA0 = &sA[(w*32)*32];
    bf16* lA1 = &sA[(w*32+16)*32];
    bf16* lB0 = &sB[(w*32)*32];
    bf16* lB1 = &sB[(w*32+16)*32];
    const int slot = lg ^ ((l16>>1)&3);
    int adA[4], adB[4];
    #pragma unroll
    for (int i=0;i<4;++i) {
        adA[i] = (wm*64 + i*16 + l16)*32 + slot*8;
        adB[i] = (wn*64 + i*16 + l16)*32 + slot*8;
    }
    f32x4 acc[4][4] = {};
    for (int ks = 0; ks < 8; ++ks) {
        gl16(gA0 + ks*32, lA0); gl16(gA1 + ks*32, lA1);
        gl16(gB0 + ks*32, lB0); gl16(gB1 + ks*32, lB1);
        __syncthreads();
        bf16x8 av[4], bv[4];
        #pragma unroll
        for (int i=0;i<4;++i) { av[i] = *(const bf16x8*)&sA[adA[i]]; bv[i] = *(const bf16x8*)&sB[adB[i]]; }
        #pragma unroll
        for (int mi=0;mi<4;++mi)
            #pragma unroll
            for (int ni=0;ni<4;++ni)
                acc[mi][ni] = mfma16(av[mi], bv[ni], acc[mi][ni]);
        __syncthreads();
    }
    #pragma unroll
    for (int ni=0;ni<4;++ni) {
        const int cg = n0 + wn*64 + ni*16 + l16;
        const int seg = cg >> 8, cs = cg & 255;
        bf16* dst = (seg==0) ? Qb : ((seg==1) ? Kb : Vb);
        const float mul = (seg==0) ? 0.1767766952966369f : 1.0f;
        const float bias = qkvb[cg];
        #pragma unroll
        for (int mi=0;mi<4;++mi) {
            const int row = m0 + wm*64 + mi*16 + lg*4;
            #pragma unroll
            for (int r=0;r<4;++r)
                dst[(size_t)(row+r)*256 + cs] = (bf16)((acc[mi][ni][r] + bias)*mul);
        }
    }
}

// ---------------------------------------------------------------------------
// window attention: one block per window, 8 heads, bias/mask from table
// ---------------------------------------------------------------------------
__global__ __launch_bounds__(256) void k_attn(
    const bf16* __restrict__ Qb, const bf16* __restrict__ Kb,
    const bf16* __restrict__ Vb, const float* __restrict__ biasTab,
    bf16* __restrict__ ao)
{
    __shared__ bf16 sK[64][264];
    __shared__ bf16 sVT[256][72];
    __shared__ bf16 sP[64][72];
    const int tid = threadIdx.x;
    const int wv = tid>>6, l = tid&63, l16 = l&15, lg = l>>4;
    const int win = blockIdx.x, b = win>>6, ww = win&63;
    const int wr = ww>>3, wc = ww&7;
    const int type = ((wr==7)?2:0) | ((wc==7)?1:0);

    for (int idx = tid; idx < 2048; idx += 256) {
        const int tok = idx>>5, c8 = idx&31;
        const int tr = tok>>3, tc = tok&7;
        const int hs = (wr*8+tr+4)&63, vs = (wc*8+tc+4)&63;
        const size_t grow = ((size_t)b<<12) + (hs<<6) + vs;
        *(bf16x8*)&sK[tok][c8*8] = *(const bf16x8*)(Kb + grow*256 + c8*8);
    }
    for (int idx = tid; idx < 2048; idx += 256) {
        const int tok = idx&63, c8 = idx>>6;
        const int tr = tok>>3, tc = tok&7;
        const int hs = (wr*8+tr+4)&63, vs = (wc*8+tc+4)&63;
        const size_t grow = ((size_t)b<<12) + (hs<<6) + vs;
        bf16x8 vvv = *(const bf16x8*)(Vb + grow*256 + c8*8);
        #pragma unroll
        for (int j=0;j<8;++j) sVT[c8*8+j][tok] = vvv[j];
    }
    const int qtok = wv*16 + l16;
    const int qtr = qtok>>3, qtc = qtok&7;
    const int qhs = (wr*8+qtr+4)&63, qvs = (wc*8+qtc+4)&63;
    const size_t qrow = ((size_t)b<<12) + (qhs<<6) + qvs;
    bf16x8 qf[8];
    #pragma unroll
    for (int h=0;h<8;++h) qf[h] = *(const bf16x8*)(Qb + qrow*256 + h*32 + lg*8);
    __syncthreads();

    const f32x4 zero = {};
    for (int h=0; h<8; ++h) {
        const float* tb = biasTab + (((type<<3) + h) << 12) + wv*16 + lg*4;
        f32x4 at[4];
        #pragma unroll
        for (int nt=0;nt<4;++nt) {
            f32x4 bias4 = *(const f32x4*)(tb + (nt*16 + l16)*64);
            at[nt] = mfma16(qf[h], *(const bf16x8*)&sK[nt*16+l16][h*32+lg*8], bias4);
        }
        #pragma unroll
        for (int r=0;r<4;++r) {
            float mx = fmaxf(fmaxf(at[0][r],at[1][r]), fmaxf(at[2][r],at[3][r]));
            #pragma unroll
            for (int ofs=8;ofs;ofs>>=1) mx = fmaxf(mx, __shfl_xor(mx,ofs));
            float e0 = __expf(at[0][r]-mx), e1 = __expf(at[1][r]-mx);
            float e2 = __expf(at[2][r]-mx), e3 = __expf(at[3][r]-mx);
            float sm = e0+e1+e2+e3;
            #pragma unroll
            for (int ofs=8;ofs;ofs>>=1) sm += __shfl_xor(sm,ofs);
            const float inv = 1.0f/sm;
            const int n = wv*16 + lg*4 + r;
            sP[n][ 0+l16] = (bf16)(e0*inv);
            sP[n][16+l16] = (bf16)(e1*inv);
            sP[n][32+l16] = (bf16)(e2*inv);
            sP[n][48+l16] = (bf16)(e3*inv);
        }
        #pragma unroll
        for (int nt=0;nt<2;++nt) {
            f32x4 o = zero;
            #pragma unroll
            for (int ks=0;ks<2;++ks) {
                bf16x8 pa = *(const bf16x8*)&sP[wv*16+l16][ks*32+lg*8];
                bf16x8 vb = *(const bf16x8*)&sVT[h*32+nt*16+l16][ks*32+lg*8];
                o = mfma16(pa, vb, o);
            }
            #pragma unroll
            for (int r=0;r<4;++r)
                ao[((size_t)win*64 + wv*16 + lg*4 + r)*256 + h*32 + nt*16 + l16] = (bf16)o[r];
        }
    }
}

// ---------------------------------------------------------------------------
// proj GEMM (128x256, K=256) + reverse-shift scatter + residual + LN2 fused
// ---------------------------------------------------------------------------
__global__ __launch_bounds__(256) void k_proj(
    const bf16* __restrict__ ao, const bf16* __restrict__ Bw,
    const float* __restrict__ projb, const float* __restrict__ x,
    const float* __restrict__ n2w, const float* __restrict__ n2b,
    float* __restrict__ out, bf16* __restrict__ xn2)
{
    __shared__ bf16 sA[128*32];
    __shared__ bf16 sB[256*32];
    const int tid = threadIdx.x, w = tid>>6, l = tid&63;
    const int l16 = l&15, lg = l>>4;
    const int m0 = blockIdx.x<<7;
    const int srow = l>>2;
    const int gk = ((l&3) ^ ((l>>3)&3)) << 3;
    const bf16* gA0 = ao + (size_t)(m0 + w*32 + srow)*256 + gk;
    const bf16* gA1 = gA0 + 16*256;
    const bf16* gB0 = Bw + (size_t)(w*64 + srow)*256 + gk;
    bf16* lA0 = &sA[(w*32)*32];
    bf16* lA1 = &sA[(w*32+16)*32];
    bf16* lB0 = &sB[(w*64)*32];
    const int slot = lg ^ ((l16>>1)&3);
    const int adA0 = (w*32 + l16)*32 + slot*8;
    const int adA1 = (w*32+16 + l16)*32 + slot*8;
    f32x4 acc[2][16] = {};
    for (int ks=0; ks<8; ++ks) {
        gl16(gA0 + ks*32, lA0); gl16(gA1 + ks*32, lA1);
        #pragma unroll
        for (int i=0;i<4;++i)
            gl16(gB0 + i*16*256 + ks*32, lB0 + i*16*32);
        __syncthreads();
        bf16x8 a0 = *(const bf16x8*)&sA[adA0];
        bf16x8 a1 = *(const bf16x8*)&sA[adA1];
        #pragma unroll
        for (int nj=0;nj<16;++nj) {
            bf16x8 bvv = *(const bf16x8*)&sB[(nj*16 + l16)*32 + slot*8];
            acc[0][nj] = mfma16(a0, bvv, acc[0][nj]);
            acc[1][nj] = mfma16(a1, bvv, acc[1][nj]);
        }
        __syncthreads();
    }
    #pragma unroll
    for (int mi=0;mi<2;++mi) {
        #pragma unroll
        for (int rr=0;rr<4;++rr) {
            const int rgw = m0 + w*32 + mi*16 + lg*4 + rr;
            const int win = rgw>>6, tok = rgw&63;
            const int bb = win>>6, wwi = win&63;
            const int wr = wwi>>3, wc = wwi&7, tr = tok>>3, tc = tok&7;
            const int hs = (wr*8+tr+4)&63, vs = (wc*8+tc+4)&63;
            const size_t grow = ((size_t)bb<<12) + (hs<<6) + vs;
            float vals[16]; float s=0.f, s2=0.f;
            #pragma unroll
            for (int nj=0;nj<16;++nj) {
                const int col = nj*16 + l16;
                const float t = acc[mi][nj][rr] + projb[col] + x[grow*256 + col];
                vals[nj] = t; s += t; s2 += t*t;
            }
            #pragma unroll
            for (int ofs=8;ofs;ofs>>=1){ s += __shfl_xor(s,ofs); s2 += __shfl_xor(s2,ofs); }
            const float mean = s*(1.f/256.f);
            const float rstd = rsqrtf(s2*(1.f/256.f) - mean*mean + 1e-5f);
            #pragma unroll
            for (int nj=0;nj<16;++nj) {
                const int col = nj*16 + l16;
                out[grow*256+col] = vals[nj];
                xn2[grow*256+col] = (bf16)((vals[nj]-mean)*rstd*n2w[col] + n2b[col]);
            }
        }
    }
}

// ---------------------------------------------------------------------------
// fused MLP: fc12 -> SiLU -> fc2 -> residual, hidden stays in LDS.
// 64-row tiles, 2048 blocks. Weights read as B-frags straight from L2.
// ---------------------------------------------------------------------------
__global__ __launch_bounds__(256) void k_mlp(
    const bf16* __restrict__ xn2, const bf16* __restrict__ w12,
    const float* __restrict__ fb12, const bf16* __restrict__ w2,
    const float* __restrict__ fb2, float* __restrict__ out)
{
    __shared__ bf16 sA[8*64*32];   // 32 KB: [ks][64][32] swizzled
    __shared__ bf16 sH[64*136];    // 17 KB: [row][128+8]
    const int tid = threadIdx.x, w = tid>>6, l = tid&63;
    const int l16 = l&15, lg = l>>4;
    const size_t m0 = (size_t)blockIdx.x << 6;
    const int srow = l>>2;
    const int gk = ((l&3) ^ ((l>>3)&3)) << 3;
    const bf16* gA = xn2 + (m0 + w*16 + srow)*256 + gk;
    #pragma unroll
    for (int ks=0; ks<8; ++ks)
        gl16(gA + ks*32, &sA[(ks*64 + w*16)*32]);

    const int slot = lg ^ ((l16>>1)&3);
    f32x4 acc2[4][4] = {};
    __syncthreads();

    for (int p=0; p<8; ++p) {
        const int hb = p*128;
        const int hc = hb + w*32;
        f32x4 ag[4][2] = {}, af[4][2] = {};
        #pragma unroll
        for (int ks=0; ks<8; ++ks) {
            bf16x8 av[4];
            #pragma unroll
            for (int m=0;m<4;++m)
                av[m] = *(const bf16x8*)&sA[(ks*64 + m*16 + l16)*32 + slot*8];
            #pragma unroll
            for (int n=0;n<2;++n) {
                const size_t gcol = hc + n*16 + l16;
                bf16x8 bg  = *(const bf16x8*)(w12 + gcol*256 + ks*32 + lg*8);
                bf16x8 bf_ = *(const bf16x8*)(w12 + (gcol+1024)*256 + ks*32 + lg*8);
                #pragma unroll
                for (int m=0;m<4;++m) {
                    ag[m][n] = mfma16(av[m], bg,  ag[m][n]);
                    af[m][n] = mfma16(av[m], bf_, af[m][n]);
                }
            }
        }
        __syncthreads();   // previous pass's sH readers done
        #pragma unroll
        for (int n=0;n<2;++n) {
            const int col = w*32 + n*16 + l16;
            const float bgv = fb12[hb + col];
            const float bfv = fb12[1024 + hb + col];
            #pragma unroll
            for (int m=0;m<4;++m) {
                #pragma unroll
                for (int r=0;r<4;++r) {
                    const float g = ag[m][n][r] + bgv;
                    const float f = af[m][n][r] + bfv;
                    sH[(m*16 + lg*4 + r)*136 + col] = (bf16)(g/(1.f+__expf(-g))*f);
                }
            }
        }
        __syncthreads();
        #pragma unroll
        for (int hk=0; hk<4; ++hk) {
            bf16x8 ah[4];
            #pragma unroll
            for (int m=0;m<4;++m)
                ah[m] = *(const bf16x8*)&sH[(m*16+l16)*136 + hk*32 + lg*8];
            #pragma unroll
            for (int n=0;n<4;++n) {
                bf16x8 bb = *(const bf16x8*)(w2 + (size_t)(w*64 + n*16 + l16)*1024
                                             + hb + hk*32 + lg*8);
                #pragma unroll
                for (int m=0;m<4;++m)
                    acc2[m][n] = mfma16(ah[m], bb, acc2[m][n]);
            }
        }
    }
    #pragma unroll
    for (int n=0;n<4;++n) {
        const int col = w*64 + n*16 + l16;
        const float bv = fb2[col];
        #pragma unroll
        for (int m=0;m<4;++m)
            #pragma unroll
            for (int r=0;r<4;++r) {
                const size_t idx = (m0 + m*16 + lg*4 + r)*256 + col;
                out[idx] += acc2[m][n][r] + bv;
            }
    }
}

// ---------------------------------------------------------------------------
extern "C" void kernel_launch(void* const* d_in, const int* in_sizes, int n_in,
                              void* d_out, int out_size, void* d_ws, size_t ws_size,
                              hipStream_t stream) {
    const float* x      = (const float*)d_in[0];
    const float* n1w    = (const float*)d_in[1];
    const float* n1b    = (const float*)d_in[2];
    const float* qkvw   = (const float*)d_in[3];
    const float* qkvb   = (const float*)d_in[4];
    const float* projw  = (const float*)d_in[5];
    const float* projb  = (const float*)d_in[6];
    const float* rpb    = (const float*)d_in[7];
    const float* n2w    = (const float*)d_in[8];
    const float* n2b    = (const float*)d_in[9];
    const float* fc12w  = (const float*)d_in[10];
    const float* fc12b  = (const float*)d_in[11];
    const float* fc2w   = (const float*)d_in[12];
    const float* fc2b   = (const float*)d_in[13];
    float* out = (float*)d_out;

    char* ws = (char*)d_ws;
    bf16* wb       = (bf16*)ws;                        // 2 MiB converted weights
    bf16* qkvw_bf  = wb;
    bf16* projw_bf = wb + 196608;
    bf16* f12w_bf  = wb + 262144;
    bf16* f2w_bf   = wb + 786432;
    float* biasTab = (float*)(ws + 2097152);           // 512 KiB
    bf16* Qb  = (bf16*)(ws + 2621440);                 // 64 MiB
    bf16* Kb  = (bf16*)(ws + 69730304);                // 64 MiB
    bf16* Vb  = (bf16*)(ws + 136839168);               // 64 MiB
    bf16* xn1 = (bf16*)(ws + 203948032);               // 64 MiB (reused as ao)
    bf16* ao  = (bf16*)(ws + 203948032);
    bf16* xn2 = (bf16*)(ws + 2621440);                 // over Qb (dead after attn)

    k_cvtw<<<1024, 256, 0, stream>>>(qkvw, projw, fc12w, fc2w, wb);
    k_mkbias<<<512, 256, 0, stream>>>(rpb, biasTab);
    k_ln<<<32768, 256, 0, stream>>>(x, n1w, n1b, xn1);
    k_qkv<<<dim3(1024, 6), 256, 0, stream>>>(xn1, qkvw_bf, qkvb, Qb, Kb, Vb);
    k_attn<<<2048, 256, 0, stream>>>(Qb, Kb, Vb, biasTab, ao);
    k_proj<<<1024, 256, 0, stream>>>(ao, projw_bf, projb, x, n2w, n2b, out, xn2);
    k_mlp<<<2048, 256, 0, stream>>>(xn2, f12w_bf, fc12b, f2w_bf, fc2b, out);
}